// Round 1
// baseline (1874.539 us; speedup 1.0000x reference)
//
#include <hip/hip_runtime.h>
#include <stdint.h>
#include <math.h>

#define VSZ 128000
#define HSZ 2048
#define BSZ 32
#define SSZ 1024
#define SOFTCAPF 30.0f
#define F32_TINY 1.17549435e-38f
#define JAX_PARTITIONABLE 1

// ---- workspace layout (bytes) ----
#define MINT_OFF  0                 // unsigned[32] encoded row max
#define ZPART_OFF 1024              // float[32*32] partial Z
#define ZVAL_OFF  5120              // float[32]
#define TBIN_OFF  5376              // int[32] threshold bin
#define CCNT_OFF  5632              // int[32] candidate counts
#define HIST_OFF  8192              // int[32*1024]
#define CAND_CAP  4096
#define CANDS_OFF 139264            // float[32*4096]
#define CANDV_OFF (139264 + 4*32*CAND_CAP)  // int[32*4096]
#define WS_ZERO   139264

// ---- ordered-float encode for atomicMax ----
__device__ inline unsigned fenc(float f) {
    unsigned u = __float_as_uint(f);
    return (u & 0x80000000u) ? ~u : (u | 0x80000000u);
}
__device__ inline float fdec(unsigned u) {
    unsigned b = (u & 0x80000000u) ? (u & 0x7FFFFFFFu) : ~u;
    return __uint_as_float(b);
}

// ---- threefry2x32, 20 rounds, matches JAX lowering exactly ----
__device__ inline void tf_round(unsigned& x0, unsigned& x1, int r) {
    x0 += x1;
    x1 = (x1 << r) | (x1 >> (32 - r));
    x1 ^= x0;
}
__device__ inline void threefry2x32(unsigned k0, unsigned k1, unsigned& x0, unsigned& x1) {
    unsigned ks2 = k0 ^ k1 ^ 0x1BD11BDAu;
    x0 += k0; x1 += k1;
    tf_round(x0,x1,13); tf_round(x0,x1,15); tf_round(x0,x1,26); tf_round(x0,x1,6);
    x0 += k1; x1 += ks2 + 1u;
    tf_round(x0,x1,17); tf_round(x0,x1,29); tf_round(x0,x1,16); tf_round(x0,x1,24);
    x0 += ks2; x1 += k0 + 2u;
    tf_round(x0,x1,13); tf_round(x0,x1,15); tf_round(x0,x1,26); tf_round(x0,x1,6);
    x0 += k0; x1 += k1 + 3u;
    tf_round(x0,x1,17); tf_round(x0,x1,29); tf_round(x0,x1,16); tf_round(x0,x1,24);
    x0 += k1; x1 += ks2 + 4u;
    tf_round(x0,x1,13); tf_round(x0,x1,15); tf_round(x0,x1,26); tf_round(x0,x1,6);
    x0 += ks2; x1 += k0 + 5u;
}

// gumbel noise for flat index j in a [B,V] f32 draw with key(42) = (0,42)
__device__ inline float gumbel_idx(unsigned j) {
#if JAX_PARTITIONABLE
    // counts = 64-bit iota -> (hi,lo) = (0, j); bits = out0 ^ out1
    unsigned x0 = 0u, x1 = j;
    threefry2x32(0u, 42u, x0, x1);
    unsigned bits = x0 ^ x1;
#else
    // legacy: counts = iota(n) split in halves, n = B*V
    const unsigned hN = (unsigned)(BSZ * VSZ / 2);
    unsigned x0, x1; bool first;
    if (j < hN) { x0 = j;      x1 = j + hN; first = true;  }
    else        { x0 = j - hN; x1 = j;      first = false; }
    threefry2x32(0u, 42u, x0, x1);
    unsigned bits = first ? x0 : x1;
#endif
    float fl = __uint_as_float((bits >> 9) | 0x3f800000u) - 1.0f;     // [0,1)
    float u  = fl * (1.0f - F32_TINY) + F32_TINY;
    u = fmaxf(F32_TINY, u);
    return -logf(-logf(u));
}

// ================= K1: GEMM + softcap + temp + row-max =================
#define BV 128
#define CH 64
#define LDE 68   // padded LDS row stride in floats

__global__ __launch_bounds__(256) void k_gemm(
    const float* __restrict__ emb, const float* __restrict__ hid,
    const int* __restrict__ pos_p, const float* __restrict__ temps,
    float* __restrict__ out, unsigned* __restrict__ Mint)
{
    __shared__ float eT[BV * LDE];   // 34816 B
    __shared__ float hT[BSZ * LDE];  // 8704 B
    __shared__ unsigned mx[BSZ];

    const int t = threadIdx.x;
    const int v0 = blockIdx.x * BV;
    const int pos = pos_p[0];
    const int vg = t & 31;     // 0..31
    const int bg = t >> 5;     // 0..7

    float acc[4][4];
#pragma unroll
    for (int i = 0; i < 4; i++)
#pragma unroll
        for (int j = 0; j < 4; j++) acc[i][j] = 0.0f;

    const int c4 = (t & 15) * 4;
    const int r0 = t >> 4;

    for (int hc = 0; hc < HSZ; hc += CH) {
        // stage embedding tile [128][64]
#pragma unroll
        for (int p = 0; p < 8; p++) {
            int r = r0 + p * 16;
            float4 d = *(const float4*)&emb[(size_t)(v0 + r) * HSZ + hc + c4];
            *(float4*)&eT[r * LDE + c4] = d;
        }
        // stage hidden tile [32][64]
#pragma unroll
        for (int p = 0; p < 2; p++) {
            int r = r0 + p * 16;
            float4 d = *(const float4*)&hid[((size_t)r * SSZ + pos) * HSZ + hc + c4];
            *(float4*)&hT[r * LDE + c4] = d;
        }
        __syncthreads();

        for (int c = 0; c < CH; c += 4) {
            float4 av[4], ab[4];
#pragma unroll
            for (int iv = 0; iv < 4; iv++) av[iv] = *(float4*)&eT[(vg + 32 * iv) * LDE + c];
#pragma unroll
            for (int ib = 0; ib < 4; ib++) ab[ib] = *(float4*)&hT[(bg + 8 * ib) * LDE + c];
#pragma unroll
            for (int ib = 0; ib < 4; ib++)
#pragma unroll
                for (int iv = 0; iv < 4; iv++) {
                    acc[ib][iv] += av[iv].x * ab[ib].x;
                    acc[ib][iv] += av[iv].y * ab[ib].y;
                    acc[ib][iv] += av[iv].z * ab[ib].z;
                    acc[ib][iv] += av[iv].w * ab[ib].w;
                }
        }
        __syncthreads();
    }

    if (t < BSZ) mx[t] = 0u;
    __syncthreads();

#pragma unroll
    for (int ib = 0; ib < 4; ib++) {
        int b = bg + 8 * ib;
        float tb = temps[b];
        unsigned lmax = 0u;
#pragma unroll
        for (int iv = 0; iv < 4; iv++) {
            float raw = acc[ib][iv];
            float sc = tanhf(raw / SOFTCAPF) * SOFTCAPF;
            float s = sc / tb;
            out[32 + (size_t)b * VSZ + (v0 + vg + 32 * iv)] = s;
            unsigned e = fenc(s);
            if (e > lmax) lmax = e;
        }
        atomicMax(&mx[b], lmax);
    }
    __syncthreads();
    if (t < BSZ) atomicMax(&Mint[t], mx[t]);
}

// ================= K2: per-row Z partials + histogram of (M - s) ========
__global__ __launch_bounds__(256) void k_stats(
    const float* __restrict__ logits, const unsigned* __restrict__ Mint,
    float* __restrict__ Zpart, int* __restrict__ hist)
{
    const int row = blockIdx.x >> 5, seg = blockIdx.x & 31;
    __shared__ int lh[1024];
    for (int i = threadIdx.x; i < 1024; i += 256) lh[i] = 0;
    __syncthreads();

    const float M = fdec(Mint[row]);
    const float* Lr = logits + (size_t)row * VSZ;
    const int beg = seg * (VSZ / 32), end = beg + (VSZ / 32);
    float sum = 0.0f;
    for (int i = beg + threadIdx.x; i < end; i += 256) {
        float s = Lr[i];
        sum += expf(s - M);
        float d = M - s;
        if (d < 16.0f) {
            int bin = (int)(d * 64.0f);
            if (bin > 1023) bin = 1023;
            atomicAdd(&lh[bin], 1);
        }
    }
    __shared__ float rs[256];
    rs[threadIdx.x] = sum; __syncthreads();
    for (int o = 128; o > 0; o >>= 1) {
        if (threadIdx.x < o) rs[threadIdx.x] += rs[threadIdx.x + o];
        __syncthreads();
    }
    if (threadIdx.x == 0) Zpart[row * 32 + seg] = rs[0];
    __syncthreads();
    for (int i = threadIdx.x; i < 1024; i += 256)
        if (lh[i]) atomicAdd(&hist[row * 1024 + i], lh[i]);
}

// ================= K3: combine Z, find threshold bin ====================
__global__ __launch_bounds__(256) void k_scan(
    const float* __restrict__ Zpart, const int* __restrict__ hist,
    float* __restrict__ Zval, int* __restrict__ Tbin)
{
    const int row = blockIdx.x;
    __shared__ int hsh[1024];
    for (int i = threadIdx.x; i < 1024; i += 256) hsh[i] = hist[row * 1024 + i];
    __syncthreads();
    if (threadIdx.x == 0) {
        float z = 0.0f;
        for (int i = 0; i < 32; i++) z += Zpart[row * 32 + i];
        Zval[row] = z;
        int cum = 0, t = 1023;
        for (int i = 0; i < 1024; i++) {
            cum += hsh[i];
            if (cum >= 63) { t = i; break; }
        }
        Tbin[row] = t;
    }
}

// ================= K4: collect candidates above threshold ===============
__global__ __launch_bounds__(256) void k_collect(
    const float* __restrict__ logits, const unsigned* __restrict__ Mint,
    const int* __restrict__ Tbin, int* __restrict__ ccnt,
    float* __restrict__ candS, int* __restrict__ candV)
{
    const int row = blockIdx.x >> 5, seg = blockIdx.x & 31;
    const float M = fdec(Mint[row]);
    const int tb = Tbin[row];
    const float* Lr = logits + (size_t)row * VSZ;
    const int beg = seg * (VSZ / 32), end = beg + (VSZ / 32);
    for (int i = beg + threadIdx.x; i < end; i += 256) {
        float s = Lr[i];
        float d = M - s;
        if (d < 16.0f) {
            int bin = (int)(d * 64.0f);
            if (bin > 1023) bin = 1023;
            if (bin <= tb) {
                int idx = atomicAdd(&ccnt[row], 1);
                if (idx < CAND_CAP) {
                    candS[row * CAND_CAP + idx] = s;
                    candV[row * CAND_CAP + idx] = i;
                }
            }
        }
    }
}

// ================= K5: top-63 sort, top-p/top-k mask, gumbel argmax =====
__global__ __launch_bounds__(256) void k_final(
    const unsigned* __restrict__ Mint, const float* __restrict__ Zval,
    const int* __restrict__ ccnt, const float* __restrict__ candS,
    const int* __restrict__ candV, const float* __restrict__ top_ps,
    const int* __restrict__ top_ks, float* __restrict__ out)
{
    const int row = blockIdx.x;
    const int tid = threadIdx.x;
    __shared__ float sS[CAND_CAP];
    __shared__ int   sV[CAND_CAP];
    __shared__ unsigned char sel[CAND_CAP];
    __shared__ float topS[64]; __shared__ int topV[64];
    __shared__ float redS[256]; __shared__ int redV[256];
    __shared__ float pArr[64]; __shared__ float scoreArr[64];
    __shared__ unsigned char kflag[64];
    __shared__ float sumKept_sh;
    __shared__ int nk_sh;

    int n = ccnt[row]; if (n > CAND_CAP) n = CAND_CAP;
    for (int i = tid; i < n; i += 256) {
        sS[i] = candS[row * CAND_CAP + i];
        sV[i] = candV[row * CAND_CAP + i];
        sel[i] = 0;
    }
    __syncthreads();

    const int nk = (n < 63) ? n : 63;
    if (tid == 0) nk_sh = nk;

    // selection sort: rank r = r-th largest s (ties -> smaller v, matching stable argsort)
    for (int r = 0; r < nk; r++) {
        float bs = -INFINITY; int bv = 0x7fffffff;
        for (int i = tid; i < n; i += 256) {
            if (!sel[i]) {
                float s = sS[i]; int v = sV[i];
                if (s > bs || (s == bs && v < bv)) { bs = s; bv = v; }
            }
        }
        redS[tid] = bs; redV[tid] = bv; __syncthreads();
        for (int o = 128; o > 0; o >>= 1) {
            if (tid < o) {
                float s2 = redS[tid + o]; int v2 = redV[tid + o];
                if (s2 > redS[tid] || (s2 == redS[tid] && v2 < redV[tid])) {
                    redS[tid] = s2; redV[tid] = v2;
                }
            }
            __syncthreads();
        }
        if (tid == 0) { topS[r] = redS[0]; topV[r] = redV[0]; }
        __syncthreads();
        for (int i = tid; i < n; i += 256)
            if (sV[i] == topV[r]) sel[i] = 1;
        __syncthreads();
    }

    // cumsum / top-p / top-k masks, exactly mirroring reference fp32 op order
    if (tid == 0) {
        float M = fdec(Mint[row]);
        float Z = Zval[row];
        float tp = top_ps[row];
        int k = top_ks[row];
        float cum = 0.0f, sk = 0.0f;
        for (int r = 0; r < nk; r++) {
            float p = expf(topS[r] - M) / Z;
            pArr[r] = p;
            cum += p;
            float before = cum - p;            // ref: cumsum - probs_sort
            bool keep = (before <= tp) && (r < k);
            kflag[r] = keep ? 1 : 0;
            if (keep) sk += p;
        }
        sumKept_sh = sk;
    }
    __syncthreads();

    // per-rank score = log(p/sumKept) + gumbel(b*V + v)
    if (tid < nk) {
        if (kflag[tid]) {
            float pf = pArr[tid] / sumKept_sh;
            unsigned j = (unsigned)(row * VSZ + topV[tid]);
            scoreArr[tid] = logf(pf) + gumbel_idx(j);
        } else {
            scoreArr[tid] = -INFINITY;
        }
    }
    __syncthreads();

    if (tid == 0) {
        float bs = -INFINITY; int bv = 0x7fffffff;
        for (int r = 0; r < nk_sh; r++) {
            float s = scoreArr[r]; int v = topV[r];
            if (s > bs || (s == bs && v < bv)) { bs = s; bv = v; }
        }
        out[row] = (float)bv;   // ids stored as float32
    }
}

// ======================================================================
extern "C" void kernel_launch(void* const* d_in, const int* in_sizes, int n_in,
                              void* d_out, int out_size, void* d_ws, size_t ws_size,
                              hipStream_t stream) {
    const float* emb   = (const float*)d_in[0];
    const float* hid   = (const float*)d_in[1];
    const int*   pos   = (const int*)d_in[2];
    const float* tps   = (const float*)d_in[3];
    const int*   tks   = (const int*)d_in[4];
    const float* temps = (const float*)d_in[5];
    float* out = (float*)d_out;
    char* ws = (char*)d_ws;

    unsigned* Mint  = (unsigned*)(ws + MINT_OFF);
    float*    Zpart = (float*)(ws + ZPART_OFF);
    float*    Zval  = (float*)(ws + ZVAL_OFF);
    int*      Tbin  = (int*)(ws + TBIN_OFF);
    int*      ccnt  = (int*)(ws + CCNT_OFF);
    int*      hist  = (int*)(ws + HIST_OFF);
    float*    candS = (float*)(ws + CANDS_OFF);
    int*      candV = (int*)(ws + CANDV_OFF);

    hipMemsetAsync(d_ws, 0, WS_ZERO, stream);

    k_gemm<<<VSZ / BV, 256, 0, stream>>>(emb, hid, pos, temps, out, Mint);
    k_stats<<<32 * 32, 256, 0, stream>>>(out + 32, Mint, Zpart, hist);
    k_scan<<<32, 256, 0, stream>>>(Zpart, hist, Zval, Tbin);
    k_collect<<<32 * 32, 256, 0, stream>>>(out + 32, Mint, Tbin, ccnt, candS, candV);
    k_final<<<32, 256, 0, stream>>>(Mint, Zval, ccnt, candS, candV, tps, tks, out);
}